// Round 5
// baseline (1002.512 us; speedup 1.0000x reference)
//
#include <hip/hip_runtime.h>
#include <hip/hip_bf16.h>
#include <math.h>

typedef unsigned short u16;
typedef __attribute__((ext_vector_type(4))) float floatx4;
typedef __attribute__((ext_vector_type(8))) short shortx8;

#define NB 64
#define NNODE 512
#define NTOT (NB*NNODE)      // 32768
#define DDIM 128
#define DEG 16
#define NEDGE (NTOT*DEG)     // 524288
#define HFF 512
#define EPSV 1e-5f
#define BFRAG_U16 16384      // 32 KB B-fragment region (u16 units)
#define EPI_LD 136           // padded epilogue row stride (u16)

__device__ __forceinline__ float bf2f(u16 u){
  union { unsigned int i; float f; } v; v.i = ((unsigned int)u) << 16; return v.f;
}
__device__ __forceinline__ u16 f2bf(float f){
  union { float f; unsigned int i; } v; v.f = f;
  unsigned int r = v.i + 0x7FFFu + ((v.i >> 16) & 1u);
  return (u16)(r >> 16);
}
__device__ __forceinline__ float gelu_f(float x){
  return 0.5f * x * (1.0f + erff(x * 0.70710678118654752f));
}

// ---------------- prep: zero counts + zero pool + cast x to bf16 ----------------
__global__ void prep_kernel(const float* __restrict__ x, u16* __restrict__ xb,
                            int* __restrict__ counts, float* __restrict__ pool){
  int gid = blockIdx.x*256 + threadIdx.x;
  if (gid < NTOT) counts[gid] = 0;
  if (gid < NB*DDIM) pool[gid] = 0.f;
  int i = gid*4;
  float4 f = *(const float4*)(x + i);
  ushort4 o; o.x = f2bf(f.x); o.y = f2bf(f.y); o.z = f2bf(f.z); o.w = f2bf(f.w);
  *(ushort4*)(xb + i) = o;
}

// ---------------- CSR build (dst-sorted) ----------------
__global__ void hist_kernel(const int* __restrict__ dst, int* __restrict__ counts){
  int e = blockIdx.x*256 + threadIdx.x; atomicAdd(&counts[dst[e]], 1);
}
__global__ void scan_kernel(const int* counts, int* row_ptr, int* cursor){
  __shared__ int part[1024];
  int t = threadIdx.x; int base = t*32;
  int loc[32]; int s = 0;
  #pragma unroll
  for (int i = 0; i < 32; ++i){ loc[i] = counts[base+i]; s += loc[i]; }
  part[t] = s; __syncthreads();
  for (int off = 1; off < 1024; off <<= 1){
    int v = (t >= off) ? part[t-off] : 0;
    __syncthreads(); part[t] += v; __syncthreads();
  }
  int run = part[t] - s;
  #pragma unroll
  for (int i = 0; i < 32; ++i){ row_ptr[base+i] = run; cursor[base+i] = run; run += loc[i]; }
  if (t == 0) row_ptr[NTOT] = part[1023];
}
__global__ void scatter_kernel(const int* __restrict__ src, const int* __restrict__ dst,
                               int* __restrict__ cursor, int* __restrict__ ssrc, int* __restrict__ seid){
  int e = blockIdx.x*256 + threadIdx.x;
  int d = dst[e];
  int pos = atomicAdd(&cursor[d], 1);
  ssrc[pos] = src[e]; seid[pos] = e;
}

// ---------------- fused 3-layer edge GEMM: 12 waves/block, reg prefetch ----------------
// All three 128x128 We staged as bf16 fragments (96 KB LDS); per-wave epilogue keeps the
// round-3-proven stride-136 layout (12 x 4.25 KB = 51 KB). Total LDS 147 KiB -> 1 block/CU,
// 3 waves/SIMD (vs 2 before). Tail: last iteration covers only 128 rows; 32-row wave slabs
// are full-or-empty so a single wrow0 guard suffices.
__global__ __launch_bounds__(768, 3)
void egemm3_kernel(const float* __restrict__ ea, const int* __restrict__ seid,
                   const float* __restrict__ We, u16* __restrict__ eout, int niter){
  __shared__ u16 bfrag[3*BFRAG_U16];        // 98304 B
  __shared__ u16 epi_s[12*16*EPI_LD];       // 52224 B
  const int t = threadIdx.x;
  const int wave = t >> 6, lane = t & 63, quad = lane >> 4, l16 = lane & 15;
  {
    const int p = wave;   // 12 waves stage exactly the 12 (layer, kk) B-fragment slabs
    const int l = p >> 2, kk = p & 3;
    const float* Bp = We + (size_t)l*DDIM*DDIM;
    #pragma unroll
    for (int nt = 0; nt < 8; ++nt){
      int colB = nt*16 + l16;
      shortx8 pk;
      #pragma unroll
      for (int j = 0; j < 8; ++j)
        pk[j] = (short)f2bf(Bp[(size_t)(kk*32 + quad*8 + j)*DDIM + colB]);
      *(shortx8*)&bfrag[((size_t)l*2048 + (kk*8 + nt)*64 + lane)*8] = pk;
    }
  }
  __syncthreads();
  u16* epi = &epi_s[wave*16*EPI_LD];
  float4 pf[16];
  int it = blockIdx.x;
  if (it < niter){
    const int w0 = it*384 + wave*32;
    if (w0 < NEDGE){
      const long br0 = (long)seid[w0 + l16], br1 = (long)seid[w0 + 16 + l16];
      #pragma unroll
      for (int kk = 0; kk < 4; ++kk){
        pf[kk*4+0] = *(const float4*)(ea + br0*DDIM + kk*32 + quad*8);
        pf[kk*4+1] = *(const float4*)(ea + br0*DDIM + kk*32 + quad*8 + 4);
        pf[kk*4+2] = *(const float4*)(ea + br1*DDIM + kk*32 + quad*8);
        pf[kk*4+3] = *(const float4*)(ea + br1*DDIM + kk*32 + quad*8 + 4);
      }
    }
  }
  while (it < niter){
    const int wrow0 = it*384 + wave*32;
    const bool valid = wrow0 < NEDGE;
    const int nxt = it + gridDim.x;
    shortx8 af[2][4];
    if (valid){
      #pragma unroll
      for (int kk = 0; kk < 4; ++kk){
        float4 x0 = pf[kk*4+0], x1 = pf[kk*4+1], y0 = pf[kk*4+2], y1 = pf[kk*4+3];
        shortx8 a0, a1;
        a0[0]=(short)f2bf(x0.x); a0[1]=(short)f2bf(x0.y); a0[2]=(short)f2bf(x0.z); a0[3]=(short)f2bf(x0.w);
        a0[4]=(short)f2bf(x1.x); a0[5]=(short)f2bf(x1.y); a0[6]=(short)f2bf(x1.z); a0[7]=(short)f2bf(x1.w);
        a1[0]=(short)f2bf(y0.x); a1[1]=(short)f2bf(y0.y); a1[2]=(short)f2bf(y0.z); a1[3]=(short)f2bf(y0.w);
        a1[4]=(short)f2bf(y1.x); a1[5]=(short)f2bf(y1.y); a1[6]=(short)f2bf(y1.z); a1[7]=(short)f2bf(y1.w);
        af[0][kk] = a0; af[1][kk] = a1;
      }
    }
    if (nxt < niter){
      const int w2 = nxt*384 + wave*32;
      if (w2 < NEDGE){
        const long br0 = (long)seid[w2 + l16], br1 = (long)seid[w2 + 16 + l16];
        #pragma unroll
        for (int kk = 0; kk < 4; ++kk){
          pf[kk*4+0] = *(const float4*)(ea + br0*DDIM + kk*32 + quad*8);
          pf[kk*4+1] = *(const float4*)(ea + br0*DDIM + kk*32 + quad*8 + 4);
          pf[kk*4+2] = *(const float4*)(ea + br1*DDIM + kk*32 + quad*8);
          pf[kk*4+3] = *(const float4*)(ea + br1*DDIM + kk*32 + quad*8 + 4);
        }
      }
    }
    if (valid){
      #pragma unroll
      for (int l = 0; l < 3; ++l){
        floatx4 acc[2][8] = {};
        #pragma unroll
        for (int kk = 0; kk < 4; ++kk){
          #pragma unroll
          for (int nt = 0; nt < 8; ++nt){
            shortx8 bfr = *(const shortx8*)&bfrag[((size_t)l*2048 + (kk*8 + nt)*64 + lane)*8];
            acc[0][nt] = __builtin_amdgcn_mfma_f32_16x16x32_bf16(af[0][kk], bfr, acc[0][nt], 0, 0, 0);
            acc[1][nt] = __builtin_amdgcn_mfma_f32_16x16x32_bf16(af[1][kk], bfr, acc[1][nt], 0, 0, 0);
          }
        }
        u16* o16 = eout + (size_t)l*NEDGE*DDIM;
        #pragma unroll
        for (int mt = 0; mt < 2; ++mt){
          #pragma unroll
          for (int nt = 0; nt < 8; ++nt){
            #pragma unroll
            for (int r = 0; r < 4; ++r)
              epi[(quad*4 + r)*EPI_LD + nt*16 + l16] = f2bf(acc[mt][nt][r]);
          }
          #pragma unroll
          for (int j = 0; j < 4; ++j){
            int row = j*4 + quad;
            uint4 d = *(const uint4*)&epi[row*EPI_LD + l16*8];
            *(uint4*)(o16 + (size_t)(wrow0 + mt*16 + row)*DDIM + l16*8) = d;
          }
        }
      }
    }
    it = nxt;
  }
}

// ---------------- K=128 barrier-free persistent GEMM, bf16 A, optional fused affine ----------------
struct Gemm2Cfg {
  const float* B[4];
  const float* bias[4];
  float* o32[4];
  u16* o16[4];
  const float* nA;     // fused GraphNorm scale  (per graph*DDIM + channel)
  const float* nBp;    // fused GraphNorm shift
  int ldb, ld_out, bcolmul, ocolmul, gelu, mtiles;
};

template<bool AFF>
__global__ __launch_bounds__(256, 3)
void gemm2_kernel(const u16* __restrict__ Ab, Gemm2Cfg cfg){
  __shared__ u16 lds[BFRAG_U16 + 4*16*EPI_LD];   // 32 KB B + 4x4.25 KB per-wave epilogue
  const int t = threadIdx.x;
  const int wave = t >> 6, lane = t & 63, quad = lane >> 4, l16 = lane & 15;
  const int cb = blockIdx.y;
  const float* Bp = cfg.B[cb];
  const int col0b = cb * cfg.bcolmul;
  {
    const int kk = wave;
    #pragma unroll
    for (int nt = 0; nt < 8; ++nt){
      int colB = col0b + nt*16 + l16;
      shortx8 pk;
      #pragma unroll
      for (int j = 0; j < 8; ++j)
        pk[j] = (short)f2bf(Bp[(size_t)(kk*32 + quad*8 + j)*cfg.ldb + colB]);
      *(shortx8*)&lds[((kk*8 + nt)*64 + lane)*8] = pk;
    }
  }
  __syncthreads();
  const float* biasp = cfg.bias[cb];
  const int col0o = cb * cfg.ocolmul;
  float bias_r[8];
  #pragma unroll
  for (int nt = 0; nt < 8; ++nt)
    bias_r[nt] = biasp ? biasp[col0o + nt*16 + l16] : 0.0f;
  u16* epi = &lds[BFRAG_U16 + wave*16*EPI_LD];

  for (int tile = blockIdx.x; tile < cfg.mtiles; tile += gridDim.x){
    const int wrow0 = tile*128 + wave*32;
    const int r0 = wrow0 + l16, r1 = r0 + 16;
    const int g = wrow0 >> 9;   // graph id; 128-row tiles never straddle 512-node graphs
    shortx8 af[2][4];
    #pragma unroll
    for (int kk = 0; kk < 4; ++kk){
      shortx8 a0 = *(const shortx8*)(Ab + (size_t)r0*128 + kk*32 + quad*8);
      shortx8 a1 = *(const shortx8*)(Ab + (size_t)r1*128 + kk*32 + quad*8);
      if (AFF){
        const float4 A0 = *(const float4*)(cfg.nA  + (size_t)g*DDIM + kk*32 + quad*8);
        const float4 A1 = *(const float4*)(cfg.nA  + (size_t)g*DDIM + kk*32 + quad*8 + 4);
        const float4 B0 = *(const float4*)(cfg.nBp + (size_t)g*DDIM + kk*32 + quad*8);
        const float4 B1 = *(const float4*)(cfg.nBp + (size_t)g*DDIM + kk*32 + quad*8 + 4);
        u16* p0 = (u16*)&a0; u16* p1 = (u16*)&a1;
        p0[0]=f2bf(bf2f(p0[0])*A0.x+B0.x); p0[1]=f2bf(bf2f(p0[1])*A0.y+B0.y);
        p0[2]=f2bf(bf2f(p0[2])*A0.z+B0.z); p0[3]=f2bf(bf2f(p0[3])*A0.w+B0.w);
        p0[4]=f2bf(bf2f(p0[4])*A1.x+B1.x); p0[5]=f2bf(bf2f(p0[5])*A1.y+B1.y);
        p0[6]=f2bf(bf2f(p0[6])*A1.z+B1.z); p0[7]=f2bf(bf2f(p0[7])*A1.w+B1.w);
        p1[0]=f2bf(bf2f(p1[0])*A0.x+B0.x); p1[1]=f2bf(bf2f(p1[1])*A0.y+B0.y);
        p1[2]=f2bf(bf2f(p1[2])*A0.z+B0.z); p1[3]=f2bf(bf2f(p1[3])*A0.w+B0.w);
        p1[4]=f2bf(bf2f(p1[4])*A1.x+B1.x); p1[5]=f2bf(bf2f(p1[5])*A1.y+B1.y);
        p1[6]=f2bf(bf2f(p1[6])*A1.z+B1.z); p1[7]=f2bf(bf2f(p1[7])*A1.w+B1.w);
      }
      af[0][kk] = a0; af[1][kk] = a1;
    }
    floatx4 acc[2][8] = {};
    #pragma unroll
    for (int kk = 0; kk < 4; ++kk){
      #pragma unroll
      for (int nt = 0; nt < 8; ++nt){
        shortx8 bfr = *(const shortx8*)&lds[((kk*8 + nt)*64 + lane)*8];
        acc[0][nt] = __builtin_amdgcn_mfma_f32_16x16x32_bf16(af[0][kk], bfr, acc[0][nt], 0, 0, 0);
        acc[1][nt] = __builtin_amdgcn_mfma_f32_16x16x32_bf16(af[1][kk], bfr, acc[1][nt], 0, 0, 0);
      }
    }
    u16* o16 = cfg.o16[cb];
    if (o16){
      #pragma unroll
      for (int mt = 0; mt < 2; ++mt){
        #pragma unroll
        for (int nt = 0; nt < 8; ++nt){
          #pragma unroll
          for (int r = 0; r < 4; ++r){
            float v = acc[mt][nt][r] + bias_r[nt];
            if (cfg.gelu) v = gelu_f(v);
            epi[(quad*4 + r)*EPI_LD + nt*16 + l16] = f2bf(v);
          }
        }
        #pragma unroll
        for (int j = 0; j < 4; ++j){
          int row = j*4 + quad;
          uint4 d = *(const uint4*)&epi[row*EPI_LD + l16*8];
          *(uint4*)(o16 + (size_t)(wrow0 + mt*16 + row)*cfg.ld_out + col0o + l16*8) = d;
        }
      }
    } else {
      float* o32 = cfg.o32[cb];
      #pragma unroll
      for (int nt = 0; nt < 8; ++nt){
        #pragma unroll
        for (int mt = 0; mt < 2; ++mt){
          #pragma unroll
          for (int r = 0; r < 4; ++r){
            int row = wrow0 + mt*16 + quad*4 + r;
            float v = acc[mt][nt][r] + bias_r[nt];
            if (cfg.gelu) v = gelu_f(v);
            o32[(size_t)row*cfg.ld_out + col0o + nt*16 + l16] = v;
          }
        }
      }
    }
  }
}

// ---------------- old K-looped GEMM (FFN2, K=512) with fused input GraphNorm ----------------
struct GemmCfg {
  const float* B[4];
  const float* bias[4];
  float* o32[4];
  u16* o16[4];
  float* pool;
  const float* nA;    // fused norm scale per (graph*K + channel); applied to A at load
  const float* nBp;
  int ldb, ld_out, K, bcolmul, ocolmul, gelu;
};

__global__ __launch_bounds__(256, 2)
void gemm_old(const u16* __restrict__ Ab, GemmCfg cfg){
  __shared__ u16 As[128][136];
  __shared__ u16 Bs[128][136];
  const int t = threadIdx.x;
  const int wave = t >> 6, lane = t & 63, quad = lane >> 4, l16 = lane & 15;
  const int row0 = blockIdx.x * 128;
  const int cb = blockIdx.y;
  const float* Bp = cfg.B[cb];
  const int col0b = cb * cfg.bcolmul;
  const int K = cfg.K;
  const int g = row0 >> 9;
  floatx4 acc[2][8] = {};
  for (int kc = 0; kc < K; kc += 128){
    #pragma unroll
    for (int j = 0; j < 8; ++j){
      int idx8 = t + j*256;
      int elem = idx8 << 3;
      int r = elem >> 7, c = elem & 127;
      uint4 d = *(const uint4*)(Ab + (size_t)(row0+r)*K + kc + c);
      if (cfg.nA){
        const float4 A0 = *(const float4*)(cfg.nA  + (size_t)g*K + kc + c);
        const float4 A1 = *(const float4*)(cfg.nA  + (size_t)g*K + kc + c + 4);
        const float4 B0 = *(const float4*)(cfg.nBp + (size_t)g*K + kc + c);
        const float4 B1 = *(const float4*)(cfg.nBp + (size_t)g*K + kc + c + 4);
        u16* pu = (u16*)&d;
        pu[0] = f2bf(bf2f(pu[0])*A0.x + B0.x);
        pu[1] = f2bf(bf2f(pu[1])*A0.y + B0.y);
        pu[2] = f2bf(bf2f(pu[2])*A0.z + B0.z);
        pu[3] = f2bf(bf2f(pu[3])*A0.w + B0.w);
        pu[4] = f2bf(bf2f(pu[4])*A1.x + B1.x);
        pu[5] = f2bf(bf2f(pu[5])*A1.y + B1.y);
        pu[6] = f2bf(bf2f(pu[6])*A1.z + B1.z);
        pu[7] = f2bf(bf2f(pu[7])*A1.w + B1.w);
      }
      *(uint4*)&As[r][c] = d;
    }
    #pragma unroll
    for (int j = 0; j < 16; ++j){
      int gi = t + j*256;
      int c = gi & 127;
      int k4 = (gi >> 7) << 2;
      size_t boff = (size_t)(kc + k4)*cfg.ldb + col0b + c;
      float f0 = Bp[boff];
      float f1 = Bp[boff + cfg.ldb];
      float f2 = Bp[boff + 2*(size_t)cfg.ldb];
      float f3 = Bp[boff + 3*(size_t)cfg.ldb];
      u16* wp = &Bs[c][k4];
      wp[0]=f2bf(f0); wp[1]=f2bf(f1); wp[2]=f2bf(f2); wp[3]=f2bf(f3);
    }
    __syncthreads();
    const int wm0 = wave*32;
    #pragma unroll
    for (int kk = 0; kk < 4; ++kk){
      shortx8 a0 = *(const shortx8*)&As[wm0 + l16][kk*32 + quad*8];
      shortx8 a1 = *(const shortx8*)&As[wm0 + 16 + l16][kk*32 + quad*8];
      #pragma unroll
      for (int nt = 0; nt < 8; ++nt){
        shortx8 bfr = *(const shortx8*)&Bs[nt*16 + l16][kk*32 + quad*8];
        acc[0][nt] = __builtin_amdgcn_mfma_f32_16x16x32_bf16(a0, bfr, acc[0][nt], 0, 0, 0);
        acc[1][nt] = __builtin_amdgcn_mfma_f32_16x16x32_bf16(a1, bfr, acc[1][nt], 0, 0, 0);
      }
    }
    __syncthreads();
  }
  const float* biasp = cfg.bias[cb];
  float* o32 = cfg.o32[cb];
  const int col0o = cb * cfg.ocolmul;
  const int wm0 = wave*32;
  float* psum = (float*)As;
  if (cfg.pool){
    __syncthreads();
    if (t < 128) psum[t] = 0.f;
    __syncthreads();
  }
  #pragma unroll
  for (int nt = 0; nt < 8; ++nt){
    int col = col0o + nt*16 + l16;
    float bvv = biasp ? biasp[col] : 0.0f;
    float cs = 0.f;
    #pragma unroll
    for (int mt = 0; mt < 2; ++mt){
      #pragma unroll
      for (int r = 0; r < 4; ++r){
        int row = row0 + wm0 + mt*16 + quad*4 + r;
        float v = acc[mt][nt][r] + bvv;
        if (cfg.gelu) v = gelu_f(v);
        o32[(size_t)row * cfg.ld_out + col] = v;
        cs += v;
      }
    }
    if (cfg.pool) atomicAdd(&psum[nt*16 + l16], cs);
  }
  if (cfg.pool){
    __syncthreads();
    if (t < 128) atomicAdd(&cfg.pool[(row0 >> 9)*DDIM + t], psum[t] * (1.0f/NNODE));
  }
}

// ---------------- attention: one wave per dst node, 2-chain online softmax, bf16 skip/out ----------------
// GELU_OUT=1: write f2bf(gelu(o)) (layers 0,1 -> next-layer pre-norm activations)
// GELU_OUT=0: write f2bf(o)       (layer 2 -> FFN1 input)
template<int GELU_OUT>
__global__ __launch_bounds__(256)
void attn_kernel(const int* __restrict__ row_ptr, const int* __restrict__ ssrc,
                 const u16* __restrict__ e_rows,
                 const u16* __restrict__ qb, const u16* __restrict__ kb, const u16* __restrict__ vb,
                 const u16* __restrict__ skip, u16* __restrict__ yout){
  int b = blockIdx.x;
  int xcd = b & 7, i = b >> 3;
  int g = xcd*8 + (i >> 7), slot = i & 127;
  int wave = threadIdx.x >> 6, lane = threadIdx.x & 63;
  int dst = g*NNODE + slot*4 + wave;
  const int ch = lane*2;
  ushort2 qp = *(const ushort2*)(qb + (size_t)dst*DDIM + ch);
  float q0 = bf2f(qp.x), q1 = bf2f(qp.y);
  int beg = row_ptr[dst], end = row_ptr[dst+1];
  float mA = -INFINITY, lA = 0.f, y0A = 0.f, y1A = 0.f;
  float mB = -INFINITY, lB = 0.f, y0B = 0.f, y1B = 0.f;
  int idx = beg;
  for (; idx + 1 < end; idx += 2){
    int s0 = ssrc[idx], s1 = ssrc[idx+1];
    ushort2 e0p = *(const ushort2*)(e_rows + (size_t)idx*DDIM + ch);
    ushort2 e1p = *(const ushort2*)(e_rows + (size_t)(idx+1)*DDIM + ch);
    ushort2 k0p = *(const ushort2*)(kb + (size_t)s0*DDIM + ch);
    ushort2 k1p = *(const ushort2*)(kb + (size_t)s1*DDIM + ch);
    ushort2 v0p = *(const ushort2*)(vb + (size_t)s0*DDIM + ch);
    ushort2 v1p = *(const ushort2*)(vb + (size_t)s1*DDIM + ch);
    {
      float e0 = bf2f(e0p.x), e1 = bf2f(e0p.y);
      float p = q0*(bf2f(k0p.x)+e0) + q1*(bf2f(k0p.y)+e1);
      p += __shfl_xor(p, 1); p += __shfl_xor(p, 2); p += __shfl_xor(p, 4);
      float sc = p * 0.25f;
      float mn = fmaxf(mA, sc);
      float cs = __expf(mA - mn), w = __expf(sc - mn);
      lA = lA*cs + w;
      y0A = y0A*cs + w*(bf2f(v0p.x)+e0);
      y1A = y1A*cs + w*(bf2f(v0p.y)+e1);
      mA = mn;
    }
    {
      float e0 = bf2f(e1p.x), e1 = bf2f(e1p.y);
      float p = q0*(bf2f(k1p.x)+e0) + q1*(bf2f(k1p.y)+e1);
      p += __shfl_xor(p, 1); p += __shfl_xor(p, 2); p += __shfl_xor(p, 4);
      float sc = p * 0.25f;
      float mn = fmaxf(mB, sc);
      float cs = __expf(mB - mn), w = __expf(sc - mn);
      lB = lB*cs + w;
      y0B = y0B*cs + w*(bf2f(v1p.x)+e0);
      y1B = y1B*cs + w*(bf2f(v1p.y)+e1);
      mB = mn;
    }
  }
  if (idx < end){
    int s0 = ssrc[idx];
    ushort2 e0p = *(const ushort2*)(e_rows + (size_t)idx*DDIM + ch);
    ushort2 k0p = *(const ushort2*)(kb + (size_t)s0*DDIM + ch);
    ushort2 v0p = *(const ushort2*)(vb + (size_t)s0*DDIM + ch);
    float e0 = bf2f(e0p.x), e1 = bf2f(e0p.y);
    float p = q0*(bf2f(k0p.x)+e0) + q1*(bf2f(k0p.y)+e1);
    p += __shfl_xor(p, 1); p += __shfl_xor(p, 2); p += __shfl_xor(p, 4);
    float sc = p * 0.25f;
    float mn = fmaxf(mA, sc);
    float cs = __expf(mA - mn), w = __expf(sc - mn);
    lA = lA*cs + w;
    y0A = y0A*cs + w*(bf2f(v0p.x)+e0);
    y1A = y1A*cs + w*(bf2f(v0p.y)+e1);
    mA = mn;
  }
  // merge chains (guard the no-edge case: both m == -inf)
  float mn = fmaxf(mA, mB);
  float cA = lA > 0.f ? __expf(mA - mn) : 0.f;
  float cB = lB > 0.f ? __expf(mB - mn) : 0.f;
  float lh = lA*cA + lB*cB;
  float a0 = y0A*cA + y0B*cB;
  float a1 = y1A*cA + y1B*cB;
  float r = lh > 0.f ? 1.0f/lh : 0.f;
  ushort2 sp = *(const ushort2*)(skip + (size_t)dst*DDIM + ch);
  float o0 = a0*r + bf2f(sp.x), o1 = a1*r + bf2f(sp.y);
  if (GELU_OUT){ o0 = gelu_f(o0); o1 = gelu_f(o1); }
  ushort2 ov; ov.x = f2bf(o0); ov.y = f2bf(o1);
  *(ushort2*)(yout + (size_t)dst*DDIM + ch) = ov;
}

// ---------------- GraphNorm (D=128, bf16 gelu'd data): 8-way split -> fused affine ----------------
__global__ __launch_bounds__(128)
void gstats_part(const u16* __restrict__ gy, float* __restrict__ ps, float* __restrict__ pq){
  int b = blockIdx.x, g = b >> 3, chunk = b & 7, c = threadIdx.x;
  const u16* base = gy + (size_t)g*NNODE*DDIM + (size_t)chunk*64*DDIM;
  float s = 0.f, q = 0.f;
  for (int i = 0; i < 64; ++i){
    float v = bf2f(base[(size_t)i*DDIM + c]);
    s += v; q += v*v;
  }
  ps[b*DDIM + c] = s; pq[b*DDIM + c] = q;
}
__global__ __launch_bounds__(128)
void gstats_comb(const float* __restrict__ ps, const float* __restrict__ pq,
                 const float* __restrict__ gamma, const float* __restrict__ beta,
                 const float* __restrict__ alpha, float* __restrict__ nA, float* __restrict__ nB){
  int g = blockIdx.x, c = threadIdx.x;
  float s = 0.f, q = 0.f;
  #pragma unroll
  for (int j = 0; j < 8; ++j){ s += ps[(g*8+j)*DDIM + c]; q += pq[(g*8+j)*DDIM + c]; }
  float mean = s * (1.f/NNODE);
  float msq  = q * (1.f/NNODE);
  float a = alpha[c];
  float invv = rsqrtf(msq - mean*mean*a*(2.f-a) + EPSV);
  float ga = gamma[c]*invv;
  nA[g*DDIM + c] = ga;
  nB[g*DDIM + c] = beta[c] - ga*a*mean;
}

// ---------------- GraphNorm (Hff=512, bf16 data): 8-way split -> fused affine ----------------
__global__ __launch_bounds__(512)
void fstats_part(const u16* __restrict__ gb, float* __restrict__ ps, float* __restrict__ pq){
  int b = blockIdx.x, g = b >> 3, chunk = b & 7, c = threadIdx.x;
  const u16* base = gb + (size_t)g*NNODE*HFF + (size_t)chunk*64*HFF;
  float s = 0.f, q = 0.f;
  for (int i = 0; i < 64; ++i){
    float v = bf2f(base[(size_t)i*HFF + c]);
    s += v; q += v*v;
  }
  ps[b*HFF + c] = s; pq[b*HFF + c] = q;
}
__global__ __launch_bounds__(512)
void fstats_comb(const float* __restrict__ ps, const float* __restrict__ pq,
                 const float* __restrict__ gamma, const float* __restrict__ beta,
                 const float* __restrict__ alpha, float* __restrict__ nA, float* __restrict__ nB){
  int g = blockIdx.x, c = threadIdx.x;
  float s = 0.f, q = 0.f;
  #pragma unroll
  for (int j = 0; j < 8; ++j){ s += ps[(g*8+j)*HFF + c]; q += pq[(g*8+j)*HFF + c]; }
  float mean = s * (1.f/NNODE);
  float msq  = q * (1.f/NNODE);
  float a = alpha[c];
  float invv = rsqrtf(msq - mean*mean*a*(2.f-a) + EPSV);
  float ga = gamma[c]*invv;
  nA[g*HFF + c] = ga;
  nB[g*HFF + c] = beta[c] - ga*a*mean;
}

extern "C" void kernel_launch(void* const* d_in, const int* in_sizes, int n_in,
                              void* d_out, int out_size, void* d_ws, size_t ws_size,
                              hipStream_t stream){
  const float* x_in = (const float*)d_in[0];
  const int*   eidx = (const int*)d_in[1];
  const float* ea   = (const float*)d_in[2];
  const float* Wq   = (const float*)d_in[4];
  const float* bq   = (const float*)d_in[5];
  const float* Wk   = (const float*)d_in[6];
  const float* bk   = (const float*)d_in[7];
  const float* Wv   = (const float*)d_in[8];
  const float* bv   = (const float*)d_in[9];
  const float* We   = (const float*)d_in[10];
  const float* Wsk  = (const float*)d_in[11];
  const float* bsk  = (const float*)d_in[12];
  const float* gn_g = (const float*)d_in[13];
  const float* gn_b = (const float*)d_in[14];
  const float* gn_a = (const float*)d_in[15];
  const float* ffW1 = (const float*)d_in[16];
  const float* ffb1 = (const float*)d_in[17];
  const float* fgn_g= (const float*)d_in[18];
  const float* fgn_b= (const float*)d_in[19];
  const float* fgn_a= (const float*)d_in[20];
  const float* ffW2 = (const float*)d_in[21];
  const float* ffb2 = (const float*)d_in[22];
  const int* srcA = eidx;
  const int* dstA = eidx + NEDGE;

  char* w = (char*)d_ws;
  auto alloc = [&](size_t bytes)->char*{ char* p = w; w += (bytes + 255) & ~(size_t)255; return p; };
  int* counts  = (int*)alloc((size_t)NTOT*4);
  int* row_ptr = (int*)alloc((size_t)(NTOT+1)*4);
  int* ssrc    = (int*)alloc((size_t)NEDGE*4);
  int* seid    = (int*)alloc((size_t)NEDGE*4);
  u16* e_bf    = (u16*)alloc((size_t)3*NEDGE*DDIM*2);  // 384 MiB: e for all 3 layers
  u16* x_bf    = (u16*)alloc((size_t)NTOT*DDIM*2);     // bf16 layer activations (x / gelu'd y / y3)
  u16* qb      = (u16*)alloc((size_t)NTOT*DDIM*2);
  u16* kb      = (u16*)alloc((size_t)NTOT*DDIM*2);
  u16* vb      = (u16*)alloc((size_t)NTOT*DDIM*2);
  u16* skipb   = (u16*)alloc((size_t)NTOT*DDIM*2);     // bf16 skip
  float* nAb   = (float*)alloc((size_t)NB*HFF*4);
  float* nBb   = (float*)alloc((size_t)NB*HFF*4);
  float* psbuf = (float*)alloc((size_t)NB*8*HFF*4);
  float* pqbuf = (float*)alloc((size_t)NB*8*HFF*4);
  u16* g_bf  = e_bf;   // FFN1 output aliases e (attn done by then)
  float* pool = (float*)d_out + (size_t)NTOT*DDIM;

  // prep (counts=0, pool=0, x->bf16) + CSR build
  prep_kernel<<<NTOT*DDIM/1024, 256, 0, stream>>>(x_in, x_bf, counts, pool);
  hist_kernel<<<NEDGE/256, 256, 0, stream>>>(dstA, counts);
  scan_kernel<<<1, 1024, 0, stream>>>(counts, row_ptr, counts);
  scatter_kernel<<<NEDGE/256, 256, 0, stream>>>(srcA, dstA, counts, ssrc, seid);

  // e_l = gather(ea) @ We[l] for all 3 layers, single pass, 12 waves/block
  egemm3_kernel<<<256, 768, 0, stream>>>(ea, seid, We, e_bf, (NEDGE + 383)/384);

  for (int l = 0; l < 3; ++l){
    // q,k,v,skip (all bf16); layers 1,2 read gelu'd bf16 with fused norm affine
    Gemm2Cfg cq = {};
    cq.B[0]=Wq + (size_t)l*DDIM*DDIM; cq.B[1]=Wk + (size_t)l*DDIM*DDIM;
    cq.B[2]=Wv + (size_t)l*DDIM*DDIM; cq.B[3]=Wsk + (size_t)l*DDIM*DDIM;
    cq.bias[0]=bq + l*DDIM; cq.bias[1]=bk + l*DDIM; cq.bias[2]=bv + l*DDIM; cq.bias[3]=bsk + l*DDIM;
    cq.o16[0]=qb; cq.o16[1]=kb; cq.o16[2]=vb; cq.o16[3]=skipb;
    cq.ldb = DDIM; cq.ld_out = DDIM; cq.bcolmul = 0; cq.ocolmul = 0; cq.gelu = 0;
    cq.mtiles = NTOT/128;
    if (l == 0){
      gemm2_kernel<false><<<dim3(NTOT/128, 4), 256, 0, stream>>>(x_bf, cq);
    } else {
      cq.nA = nAb; cq.nBp = nBb;
      gemm2_kernel<true><<<dim3(NTOT/128, 4), 256, 0, stream>>>(x_bf, cq);
    }

    if (l < 2){
      attn_kernel<1><<<NTOT/4, 256, 0, stream>>>(row_ptr, ssrc,
          e_bf + (size_t)l*NEDGE*DDIM, qb, kb, vb, skipb, x_bf);
      gstats_part<<<NB*8, 128, 0, stream>>>(x_bf, psbuf, pqbuf);
      gstats_comb<<<NB, 128, 0, stream>>>(psbuf, pqbuf,
          gn_g + l*DDIM, gn_b + l*DDIM, gn_a + l*DDIM, nAb, nBb);
    } else {
      attn_kernel<0><<<NTOT/4, 256, 0, stream>>>(row_ptr, ssrc,
          e_bf + (size_t)l*NEDGE*DDIM, qb, kb, vb, skipb, x_bf);
    }
  }

  // FFN1: g = gelu(y3 @ ffW1 + ffb1) (bf16, aliases e region); A = y3 bf16
  Gemm2Cfg c1 = {};
  for (int i2 = 0; i2 < 4; ++i2){ c1.B[i2] = ffW1; c1.bias[i2] = ffb1; c1.o16[i2] = g_bf; }
  c1.ldb = HFF; c1.ld_out = HFF; c1.bcolmul = 128; c1.ocolmul = 128; c1.gelu = 1;
  c1.mtiles = NTOT/128;
  gemm2_kernel<false><<<dim3(NTOT/128, 4), 256, 0, stream>>>(x_bf, c1);

  fstats_part<<<NB*8, 512, 0, stream>>>(g_bf, psbuf, pqbuf);
  fstats_comb<<<NB, 512, 0, stream>>>(psbuf, pqbuf, fgn_g, fgn_b, fgn_a, nAb, nBb);

  // FFN2 (K=512): x_out = norm(g) @ ffW2 + ffb2 -> d_out, norm fused into A-staging, fused mean-pool
  GemmCfg c2 = {};
  for (int i2 = 0; i2 < 4; ++i2){ c2.B[i2] = ffW2; c2.bias[i2] = ffb2; c2.o32[i2] = (float*)d_out; }
  c2.ldb = DDIM; c2.ld_out = DDIM; c2.K = HFF; c2.bcolmul = 0; c2.ocolmul = 0; c2.gelu = 0;
  c2.pool = pool;
  c2.nA = nAb; c2.nBp = nBb;
  gemm_old<<<dim3(NTOT/128, 1), 256, 0, stream>>>(g_bf, c2);
}

// Round 6
// 920.673 us; speedup vs baseline: 1.0889x; 1.0889x over previous
//
#include <hip/hip_runtime.h>
#include <hip/hip_bf16.h>
#include <math.h>

typedef unsigned short u16;
typedef __attribute__((ext_vector_type(4))) float floatx4;
typedef __attribute__((ext_vector_type(8))) short shortx8;

#define NB 64
#define NNODE 512
#define NTOT (NB*NNODE)      // 32768
#define DDIM 128
#define DEG 16
#define NEDGE (NTOT*DEG)     // 524288
#define HFF 512
#define EPSV 1e-5f
#define BFRAG_U16 16384      // 32 KB B-fragment region (u16 units)
#define EPI_LD 136           // padded epilogue row stride (u16)

__device__ __forceinline__ float bf2f(u16 u){
  union { unsigned int i; float f; } v; v.i = ((unsigned int)u) << 16; return v.f;
}
__device__ __forceinline__ u16 f2bf(float f){
  union { float f; unsigned int i; } v; v.f = f;
  unsigned int r = v.i + 0x7FFFu + ((v.i >> 16) & 1u);
  return (u16)(r >> 16);
}
__device__ __forceinline__ float gelu_f(float x){
  return 0.5f * x * (1.0f + erff(x * 0.70710678118654752f));
}

// ---------------- prep: zero counts + zero pool + cast x to bf16 ----------------
__global__ void prep_kernel(const float* __restrict__ x, u16* __restrict__ xb,
                            int* __restrict__ counts, float* __restrict__ pool){
  int gid = blockIdx.x*256 + threadIdx.x;
  if (gid < NTOT) counts[gid] = 0;
  if (gid < NB*DDIM) pool[gid] = 0.f;
  int i = gid*4;
  float4 f = *(const float4*)(x + i);
  ushort4 o; o.x = f2bf(f.x); o.y = f2bf(f.y); o.z = f2bf(f.z); o.w = f2bf(f.w);
  *(ushort4*)(xb + i) = o;
}

// ---------------- CSR build (dst-sorted) ----------------
__global__ void hist_kernel(const int* __restrict__ dst, int* __restrict__ counts){
  int e = blockIdx.x*256 + threadIdx.x; atomicAdd(&counts[dst[e]], 1);
}
__global__ void scan_kernel(const int* counts, int* row_ptr, int* cursor){
  __shared__ int part[1024];
  int t = threadIdx.x; int base = t*32;
  int loc[32]; int s = 0;
  #pragma unroll
  for (int i = 0; i < 32; ++i){ loc[i] = counts[base+i]; s += loc[i]; }
  part[t] = s; __syncthreads();
  for (int off = 1; off < 1024; off <<= 1){
    int v = (t >= off) ? part[t-off] : 0;
    __syncthreads(); part[t] += v; __syncthreads();
  }
  int run = part[t] - s;
  #pragma unroll
  for (int i = 0; i < 32; ++i){ row_ptr[base+i] = run; cursor[base+i] = run; run += loc[i]; }
  if (t == 0) row_ptr[NTOT] = part[1023];
}
// also emits inverse permutation inv[orig_edge] = sorted_pos for scatter-write e-GEMM
__global__ void scatter_kernel(const int* __restrict__ src, const int* __restrict__ dst,
                               int* __restrict__ cursor, int* __restrict__ ssrc,
                               int* __restrict__ inv){
  int e = blockIdx.x*256 + threadIdx.x;
  int d = dst[e];
  int pos = atomicAdd(&cursor[d], 1);
  ssrc[pos] = src[e]; inv[e] = pos;
}

// ---------------- fused 3-layer edge GEMM: streaming reads, scatter writes ----------------
// 8 waves/block (round-3-proven geometry/LDS). A rows processed in ORIGINAL edge order ->
// perfectly coalesced streaming float4 reads (no gather latency on the critical path).
// Output rows scattered to dst-sorted positions via inv[] (256B-aligned full-line writes,
// fire-and-forget). 1-deep register prefetch of the next tile's A overlaps the MFMAs.
__global__ __launch_bounds__(512, 2)
void egemm3_kernel(const float* __restrict__ ea, const int* __restrict__ inv,
                   const float* __restrict__ We, u16* __restrict__ eout, int niter){
  __shared__ u16 bfrag[3*BFRAG_U16];        // 98304 B
  __shared__ u16 epi_s[8*16*EPI_LD];        // 34816 B
  const int t = threadIdx.x;
  const int wave = t >> 6, lane = t & 63, quad = lane >> 4, l16 = lane & 15;
  for (int p = wave; p < 12; p += 8){
    const int l = p >> 2, kk = p & 3;
    const float* Bp = We + (size_t)l*DDIM*DDIM;
    #pragma unroll
    for (int nt = 0; nt < 8; ++nt){
      int colB = nt*16 + l16;
      shortx8 pk;
      #pragma unroll
      for (int j = 0; j < 8; ++j)
        pk[j] = (short)f2bf(Bp[(size_t)(kk*32 + quad*8 + j)*DDIM + colB]);
      *(shortx8*)&bfrag[((size_t)l*2048 + (kk*8 + nt)*64 + lane)*8] = pk;
    }
  }
  __syncthreads();
  u16* epi = &epi_s[wave*16*EPI_LD];
  float4 pf[16];
  int it = blockIdx.x;
  if (it < niter){
    const size_t base = ((size_t)it*256 + wave*32)*DDIM;
    #pragma unroll
    for (int kk = 0; kk < 4; ++kk){
      pf[kk*4+0] = *(const float4*)(ea + base + (size_t)l16*DDIM + kk*32 + quad*8);
      pf[kk*4+1] = *(const float4*)(ea + base + (size_t)l16*DDIM + kk*32 + quad*8 + 4);
      pf[kk*4+2] = *(const float4*)(ea + base + (size_t)(16 + l16)*DDIM + kk*32 + quad*8);
      pf[kk*4+3] = *(const float4*)(ea + base + (size_t)(16 + l16)*DDIM + kk*32 + quad*8 + 4);
    }
  }
  while (it < niter){
    const int wrow0 = it*256 + wave*32;
    const int nxt = it + gridDim.x;
    shortx8 af[2][4];
    #pragma unroll
    for (int kk = 0; kk < 4; ++kk){
      float4 x0 = pf[kk*4+0], x1 = pf[kk*4+1], y0 = pf[kk*4+2], y1 = pf[kk*4+3];
      shortx8 a0, a1;
      a0[0]=(short)f2bf(x0.x); a0[1]=(short)f2bf(x0.y); a0[2]=(short)f2bf(x0.z); a0[3]=(short)f2bf(x0.w);
      a0[4]=(short)f2bf(x1.x); a0[5]=(short)f2bf(x1.y); a0[6]=(short)f2bf(x1.z); a0[7]=(short)f2bf(x1.w);
      a1[0]=(short)f2bf(y0.x); a1[1]=(short)f2bf(y0.y); a1[2]=(short)f2bf(y0.z); a1[3]=(short)f2bf(y0.w);
      a1[4]=(short)f2bf(y1.x); a1[5]=(short)f2bf(y1.y); a1[6]=(short)f2bf(y1.z); a1[7]=(short)f2bf(y1.w);
      af[0][kk] = a0; af[1][kk] = a1;
    }
    if (nxt < niter){
      const size_t base = ((size_t)nxt*256 + wave*32)*DDIM;
      #pragma unroll
      for (int kk = 0; kk < 4; ++kk){
        pf[kk*4+0] = *(const float4*)(ea + base + (size_t)l16*DDIM + kk*32 + quad*8);
        pf[kk*4+1] = *(const float4*)(ea + base + (size_t)l16*DDIM + kk*32 + quad*8 + 4);
        pf[kk*4+2] = *(const float4*)(ea + base + (size_t)(16 + l16)*DDIM + kk*32 + quad*8);
        pf[kk*4+3] = *(const float4*)(ea + base + (size_t)(16 + l16)*DDIM + kk*32 + quad*8 + 4);
      }
    }
    // destination (dst-sorted) rows for this tile's 32 original-order rows
    int drow[2][4];
    #pragma unroll
    for (int mt = 0; mt < 2; ++mt)
      #pragma unroll
      for (int j = 0; j < 4; ++j)
        drow[mt][j] = inv[wrow0 + mt*16 + j*4 + quad];
    #pragma unroll
    for (int l = 0; l < 3; ++l){
      floatx4 acc[2][8] = {};
      #pragma unroll
      for (int kk = 0; kk < 4; ++kk){
        #pragma unroll
        for (int nt = 0; nt < 8; ++nt){
          shortx8 bfr = *(const shortx8*)&bfrag[((size_t)l*2048 + (kk*8 + nt)*64 + lane)*8];
          acc[0][nt] = __builtin_amdgcn_mfma_f32_16x16x32_bf16(af[0][kk], bfr, acc[0][nt], 0, 0, 0);
          acc[1][nt] = __builtin_amdgcn_mfma_f32_16x16x32_bf16(af[1][kk], bfr, acc[1][nt], 0, 0, 0);
        }
      }
      u16* o16 = eout + (size_t)l*NEDGE*DDIM;
      #pragma unroll
      for (int mt = 0; mt < 2; ++mt){
        #pragma unroll
        for (int nt = 0; nt < 8; ++nt){
          #pragma unroll
          for (int r = 0; r < 4; ++r)
            epi[(quad*4 + r)*EPI_LD + nt*16 + l16] = f2bf(acc[mt][nt][r]);
        }
        #pragma unroll
        for (int j = 0; j < 4; ++j){
          uint4 d = *(const uint4*)&epi[(j*4 + quad)*EPI_LD + l16*8];
          *(uint4*)(o16 + (size_t)drow[mt][j]*DDIM + l16*8) = d;
        }
      }
    }
    it = nxt;
  }
}

// ---------------- K=128 barrier-free persistent GEMM, bf16 A, optional fused affine ----------------
struct Gemm2Cfg {
  const float* B[4];
  const float* bias[4];
  float* o32[4];
  u16* o16[4];
  const float* nA;     // fused GraphNorm scale  (per graph*DDIM + channel)
  const float* nBp;    // fused GraphNorm shift
  int ldb, ld_out, bcolmul, ocolmul, gelu, mtiles;
};

template<bool AFF>
__global__ __launch_bounds__(256, 3)
void gemm2_kernel(const u16* __restrict__ Ab, Gemm2Cfg cfg){
  __shared__ u16 lds[BFRAG_U16 + 4*16*EPI_LD];   // 32 KB B + 4x4.25 KB per-wave epilogue
  const int t = threadIdx.x;
  const int wave = t >> 6, lane = t & 63, quad = lane >> 4, l16 = lane & 15;
  const int cb = blockIdx.y;
  const float* Bp = cfg.B[cb];
  const int col0b = cb * cfg.bcolmul;
  {
    const int kk = wave;
    #pragma unroll
    for (int nt = 0; nt < 8; ++nt){
      int colB = col0b + nt*16 + l16;
      shortx8 pk;
      #pragma unroll
      for (int j = 0; j < 8; ++j)
        pk[j] = (short)f2bf(Bp[(size_t)(kk*32 + quad*8 + j)*cfg.ldb + colB]);
      *(shortx8*)&lds[((kk*8 + nt)*64 + lane)*8] = pk;
    }
  }
  __syncthreads();
  const float* biasp = cfg.bias[cb];
  const int col0o = cb * cfg.ocolmul;
  float bias_r[8];
  #pragma unroll
  for (int nt = 0; nt < 8; ++nt)
    bias_r[nt] = biasp ? biasp[col0o + nt*16 + l16] : 0.0f;
  u16* epi = &lds[BFRAG_U16 + wave*16*EPI_LD];

  for (int tile = blockIdx.x; tile < cfg.mtiles; tile += gridDim.x){
    const int wrow0 = tile*128 + wave*32;
    const int r0 = wrow0 + l16, r1 = r0 + 16;
    const int g = wrow0 >> 9;   // graph id; 128-row tiles never straddle 512-node graphs
    shortx8 af[2][4];
    #pragma unroll
    for (int kk = 0; kk < 4; ++kk){
      shortx8 a0 = *(const shortx8*)(Ab + (size_t)r0*128 + kk*32 + quad*8);
      shortx8 a1 = *(const shortx8*)(Ab + (size_t)r1*128 + kk*32 + quad*8);
      if (AFF){
        const float4 A0 = *(const float4*)(cfg.nA  + (size_t)g*DDIM + kk*32 + quad*8);
        const float4 A1 = *(const float4*)(cfg.nA  + (size_t)g*DDIM + kk*32 + quad*8 + 4);
        const float4 B0 = *(const float4*)(cfg.nBp + (size_t)g*DDIM + kk*32 + quad*8);
        const float4 B1 = *(const float4*)(cfg.nBp + (size_t)g*DDIM + kk*32 + quad*8 + 4);
        u16* p0 = (u16*)&a0; u16* p1 = (u16*)&a1;
        p0[0]=f2bf(bf2f(p0[0])*A0.x+B0.x); p0[1]=f2bf(bf2f(p0[1])*A0.y+B0.y);
        p0[2]=f2bf(bf2f(p0[2])*A0.z+B0.z); p0[3]=f2bf(bf2f(p0[3])*A0.w+B0.w);
        p0[4]=f2bf(bf2f(p0[4])*A1.x+B1.x); p0[5]=f2bf(bf2f(p0[5])*A1.y+B1.y);
        p0[6]=f2bf(bf2f(p0[6])*A1.z+B1.z); p0[7]=f2bf(bf2f(p0[7])*A1.w+B1.w);
        p1[0]=f2bf(bf2f(p1[0])*A0.x+B0.x); p1[1]=f2bf(bf2f(p1[1])*A0.y+B0.y);
        p1[2]=f2bf(bf2f(p1[2])*A0.z+B0.z); p1[3]=f2bf(bf2f(p1[3])*A0.w+B0.w);
        p1[4]=f2bf(bf2f(p1[4])*A1.x+B1.x); p1[5]=f2bf(bf2f(p1[5])*A1.y+B1.y);
        p1[6]=f2bf(bf2f(p1[6])*A1.z+B1.z); p1[7]=f2bf(bf2f(p1[7])*A1.w+B1.w);
      }
      af[0][kk] = a0; af[1][kk] = a1;
    }
    floatx4 acc[2][8] = {};
    #pragma unroll
    for (int kk = 0; kk < 4; ++kk){
      #pragma unroll
      for (int nt = 0; nt < 8; ++nt){
        shortx8 bfr = *(const shortx8*)&lds[((kk*8 + nt)*64 + lane)*8];
        acc[0][nt] = __builtin_amdgcn_mfma_f32_16x16x32_bf16(af[0][kk], bfr, acc[0][nt], 0, 0, 0);
        acc[1][nt] = __builtin_amdgcn_mfma_f32_16x16x32_bf16(af[1][kk], bfr, acc[1][nt], 0, 0, 0);
      }
    }
    u16* o16 = cfg.o16[cb];
    if (o16){
      #pragma unroll
      for (int mt = 0; mt < 2; ++mt){
        #pragma unroll
        for (int nt = 0; nt < 8; ++nt){
          #pragma unroll
          for (int r = 0; r < 4; ++r){
            float v = acc[mt][nt][r] + bias_r[nt];
            if (cfg.gelu) v = gelu_f(v);
            epi[(quad*4 + r)*EPI_LD + nt*16 + l16] = f2bf(v);
          }
        }
        #pragma unroll
        for (int j = 0; j < 4; ++j){
          int row = j*4 + quad;
          uint4 d = *(const uint4*)&epi[row*EPI_LD + l16*8];
          *(uint4*)(o16 + (size_t)(wrow0 + mt*16 + row)*cfg.ld_out + col0o + l16*8) = d;
        }
      }
    } else {
      float* o32 = cfg.o32[cb];
      #pragma unroll
      for (int nt = 0; nt < 8; ++nt){
        #pragma unroll
        for (int mt = 0; mt < 2; ++mt){
          #pragma unroll
          for (int r = 0; r < 4; ++r){
            int row = wrow0 + mt*16 + quad*4 + r;
            float v = acc[mt][nt][r] + bias_r[nt];
            if (cfg.gelu) v = gelu_f(v);
            o32[(size_t)row*cfg.ld_out + col0o + nt*16 + l16] = v;
          }
        }
      }
    }
  }
}

// ---------------- old K-looped GEMM (FFN2, K=512) with fused input GraphNorm ----------------
struct GemmCfg {
  const float* B[4];
  const float* bias[4];
  float* o32[4];
  u16* o16[4];
  float* pool;
  const float* nA;    // fused norm scale per (graph*K + channel); applied to A at load
  const float* nBp;
  int ldb, ld_out, K, bcolmul, ocolmul, gelu;
};

__global__ __launch_bounds__(256, 2)
void gemm_old(const u16* __restrict__ Ab, GemmCfg cfg){
  __shared__ u16 As[128][136];
  __shared__ u16 Bs[128][136];
  const int t = threadIdx.x;
  const int wave = t >> 6, lane = t & 63, quad = lane >> 4, l16 = lane & 15;
  const int row0 = blockIdx.x * 128;
  const int cb = blockIdx.y;
  const float* Bp = cfg.B[cb];
  const int col0b = cb * cfg.bcolmul;
  const int K = cfg.K;
  const int g = row0 >> 9;
  floatx4 acc[2][8] = {};
  for (int kc = 0; kc < K; kc += 128){
    #pragma unroll
    for (int j = 0; j < 8; ++j){
      int idx8 = t + j*256;
      int elem = idx8 << 3;
      int r = elem >> 7, c = elem & 127;
      uint4 d = *(const uint4*)(Ab + (size_t)(row0+r)*K + kc + c);
      if (cfg.nA){
        const float4 A0 = *(const float4*)(cfg.nA  + (size_t)g*K + kc + c);
        const float4 A1 = *(const float4*)(cfg.nA  + (size_t)g*K + kc + c + 4);
        const float4 B0 = *(const float4*)(cfg.nBp + (size_t)g*K + kc + c);
        const float4 B1 = *(const float4*)(cfg.nBp + (size_t)g*K + kc + c + 4);
        u16* pu = (u16*)&d;
        pu[0] = f2bf(bf2f(pu[0])*A0.x + B0.x);
        pu[1] = f2bf(bf2f(pu[1])*A0.y + B0.y);
        pu[2] = f2bf(bf2f(pu[2])*A0.z + B0.z);
        pu[3] = f2bf(bf2f(pu[3])*A0.w + B0.w);
        pu[4] = f2bf(bf2f(pu[4])*A1.x + B1.x);
        pu[5] = f2bf(bf2f(pu[5])*A1.y + B1.y);
        pu[6] = f2bf(bf2f(pu[6])*A1.z + B1.z);
        pu[7] = f2bf(bf2f(pu[7])*A1.w + B1.w);
      }
      *(uint4*)&As[r][c] = d;
    }
    #pragma unroll
    for (int j = 0; j < 16; ++j){
      int gi = t + j*256;
      int c = gi & 127;
      int k4 = (gi >> 7) << 2;
      size_t boff = (size_t)(kc + k4)*cfg.ldb + col0b + c;
      float f0 = Bp[boff];
      float f1 = Bp[boff + cfg.ldb];
      float f2 = Bp[boff + 2*(size_t)cfg.ldb];
      float f3 = Bp[boff + 3*(size_t)cfg.ldb];
      u16* wp = &Bs[c][k4];
      wp[0]=f2bf(f0); wp[1]=f2bf(f1); wp[2]=f2bf(f2); wp[3]=f2bf(f3);
    }
    __syncthreads();
    const int wm0 = wave*32;
    #pragma unroll
    for (int kk = 0; kk < 4; ++kk){
      shortx8 a0 = *(const shortx8*)&As[wm0 + l16][kk*32 + quad*8];
      shortx8 a1 = *(const shortx8*)&As[wm0 + 16 + l16][kk*32 + quad*8];
      #pragma unroll
      for (int nt = 0; nt < 8; ++nt){
        shortx8 bfr = *(const shortx8*)&Bs[nt*16 + l16][kk*32 + quad*8];
        acc[0][nt] = __builtin_amdgcn_mfma_f32_16x16x32_bf16(a0, bfr, acc[0][nt], 0, 0, 0);
        acc[1][nt] = __builtin_amdgcn_mfma_f32_16x16x32_bf16(a1, bfr, acc[1][nt], 0, 0, 0);
      }
    }
    __syncthreads();
  }
  const float* biasp = cfg.bias[cb];
  float* o32 = cfg.o32[cb];
  const int col0o = cb * cfg.ocolmul;
  const int wm0 = wave*32;
  float* psum = (float*)As;
  if (cfg.pool){
    __syncthreads();
    if (t < 128) psum[t] = 0.f;
    __syncthreads();
  }
  #pragma unroll
  for (int nt = 0; nt < 8; ++nt){
    int col = col0o + nt*16 + l16;
    float bvv = biasp ? biasp[col] : 0.0f;
    float cs = 0.f;
    #pragma unroll
    for (int mt = 0; mt < 2; ++mt){
      #pragma unroll
      for (int r = 0; r < 4; ++r){
        int row = row0 + wm0 + mt*16 + quad*4 + r;
        float v = acc[mt][nt][r] + bvv;
        if (cfg.gelu) v = gelu_f(v);
        o32[(size_t)row * cfg.ld_out + col] = v;
        cs += v;
      }
    }
    if (cfg.pool) atomicAdd(&psum[nt*16 + l16], cs);
  }
  if (cfg.pool){
    __syncthreads();
    if (t < 128) atomicAdd(&cfg.pool[(row0 >> 9)*DDIM + t], psum[t] * (1.0f/NNODE));
  }
}

// ---------------- attention: one wave per dst node, 2-chain online softmax, bf16 skip/out ----------------
// GELU_OUT=1: write f2bf(gelu(o)) (layers 0,1 -> next-layer pre-norm activations)
// GELU_OUT=0: write f2bf(o)       (layer 2 -> FFN1 input)
template<int GELU_OUT>
__global__ __launch_bounds__(256)
void attn_kernel(const int* __restrict__ row_ptr, const int* __restrict__ ssrc,
                 const u16* __restrict__ e_rows,
                 const u16* __restrict__ qb, const u16* __restrict__ kb, const u16* __restrict__ vb,
                 const u16* __restrict__ skip, u16* __restrict__ yout){
  int b = blockIdx.x;
  int xcd = b & 7, i = b >> 3;
  int g = xcd*8 + (i >> 7), slot = i & 127;
  int wave = threadIdx.x >> 6, lane = threadIdx.x & 63;
  int dst = g*NNODE + slot*4 + wave;
  const int ch = lane*2;
  ushort2 qp = *(const ushort2*)(qb + (size_t)dst*DDIM + ch);
  float q0 = bf2f(qp.x), q1 = bf2f(qp.y);
  int beg = row_ptr[dst], end = row_ptr[dst+1];
  float mA = -INFINITY, lA = 0.f, y0A = 0.f, y1A = 0.f;
  float mB = -INFINITY, lB = 0.f, y0B = 0.f, y1B = 0.f;
  int idx = beg;
  for (; idx + 1 < end; idx += 2){
    int s0 = ssrc[idx], s1 = ssrc[idx+1];
    ushort2 e0p = *(const ushort2*)(e_rows + (size_t)idx*DDIM + ch);
    ushort2 e1p = *(const ushort2*)(e_rows + (size_t)(idx+1)*DDIM + ch);
    ushort2 k0p = *(const ushort2*)(kb + (size_t)s0*DDIM + ch);
    ushort2 k1p = *(const ushort2*)(kb + (size_t)s1*DDIM + ch);
    ushort2 v0p = *(const ushort2*)(vb + (size_t)s0*DDIM + ch);
    ushort2 v1p = *(const ushort2*)(vb + (size_t)s1*DDIM + ch);
    {
      float e0 = bf2f(e0p.x), e1 = bf2f(e0p.y);
      float p = q0*(bf2f(k0p.x)+e0) + q1*(bf2f(k0p.y)+e1);
      p += __shfl_xor(p, 1); p += __shfl_xor(p, 2); p += __shfl_xor(p, 4);
      float sc = p * 0.25f;
      float mn = fmaxf(mA, sc);
      float cs = __expf(mA - mn), w = __expf(sc - mn);
      lA = lA*cs + w;
      y0A = y0A*cs + w*(bf2f(v0p.x)+e0);
      y1A = y1A*cs + w*(bf2f(v0p.y)+e1);
      mA = mn;
    }
    {
      float e0 = bf2f(e1p.x), e1 = bf2f(e1p.y);
      float p = q0*(bf2f(k1p.x)+e0) + q1*(bf2f(k1p.y)+e1);
      p += __shfl_xor(p, 1); p += __shfl_xor(p, 2); p += __shfl_xor(p, 4);
      float sc = p * 0.25f;
      float mn = fmaxf(mB, sc);
      float cs = __expf(mB - mn), w = __expf(sc - mn);
      lB = lB*cs + w;
      y0B = y0B*cs + w*(bf2f(v1p.x)+e0);
      y1B = y1B*cs + w*(bf2f(v1p.y)+e1);
      mB = mn;
    }
  }
  if (idx < end){
    int s0 = ssrc[idx];
    ushort2 e0p = *(const ushort2*)(e_rows + (size_t)idx*DDIM + ch);
    ushort2 k0p = *(const ushort2*)(kb + (size_t)s0*DDIM + ch);
    ushort2 v0p = *(const ushort2*)(vb + (size_t)s0*DDIM + ch);
    float e0 = bf2f(e0p.x), e1 = bf2f(e0p.y);
    float p = q0*(bf2f(k0p.x)+e0) + q1*(bf2f(k0p.y)+e1);
    p += __shfl_xor(p, 1); p += __shfl_xor(p, 2); p += __shfl_xor(p, 4);
    float sc = p * 0.25f;
    float mn = fmaxf(mA, sc);
    float cs = __expf(mA - mn), w = __expf(sc - mn);
    lA = lA*cs + w;
    y0A = y0A*cs + w*(bf2f(v0p.x)+e0);
    y1A = y1A*cs + w*(bf2f(v0p.y)+e1);
    mA = mn;
  }
  // merge chains (guard the no-edge case: both m == -inf)
  float mn = fmaxf(mA, mB);
  float cA = lA > 0.f ? __expf(mA - mn) : 0.f;
  float cB = lB > 0.f ? __expf(mB - mn) : 0.f;
  float lh = lA*cA + lB*cB;
  float a0 = y0A*cA + y0B*cB;
  float a1 = y1A*cA + y1B*cB;
  float r = lh > 0.f ? 1.0f/lh : 0.f;
  ushort2 sp = *(const ushort2*)(skip + (size_t)dst*DDIM + ch);
  float o0 = a0*r + bf2f(sp.x), o1 = a1*r + bf2f(sp.y);
  if (GELU_OUT){ o0 = gelu_f(o0); o1 = gelu_f(o1); }
  ushort2 ov; ov.x = f2bf(o0); ov.y = f2bf(o1);
  *(ushort2*)(yout + (size_t)dst*DDIM + ch) = ov;
}

// ---------------- GraphNorm (D=128, bf16 gelu'd data): 8-way split -> fused affine ----------------
__global__ __launch_bounds__(128)
void gstats_part(const u16* __restrict__ gy, float* __restrict__ ps, float* __restrict__ pq){
  int b = blockIdx.x, g = b >> 3, chunk = b & 7, c = threadIdx.x;
  const u16* base = gy + (size_t)g*NNODE*DDIM + (size_t)chunk*64*DDIM;
  float s = 0.f, q = 0.f;
  for (int i = 0; i < 64; ++i){
    float v = bf2f(base[(size_t)i*DDIM + c]);
    s += v; q += v*v;
  }
  ps[b*DDIM + c] = s; pq[b*DDIM + c] = q;
}
__global__ __launch_bounds__(128)
void gstats_comb(const float* __restrict__ ps, const float* __restrict__ pq,
                 const float* __restrict__ gamma, const float* __restrict__ beta,
                 const float* __restrict__ alpha, float* __restrict__ nA, float* __restrict__ nB){
  int g = blockIdx.x, c = threadIdx.x;
  float s = 0.f, q = 0.f;
  #pragma unroll
  for (int j = 0; j < 8; ++j){ s += ps[(g*8+j)*DDIM + c]; q += pq[(g*8+j)*DDIM + c]; }
  float mean = s * (1.f/NNODE);
  float msq  = q * (1.f/NNODE);
  float a = alpha[c];
  float invv = rsqrtf(msq - mean*mean*a*(2.f-a) + EPSV);
  float ga = gamma[c]*invv;
  nA[g*DDIM + c] = ga;
  nB[g*DDIM + c] = beta[c] - ga*a*mean;
}

// ---------------- GraphNorm (Hff=512, bf16 data): 8-way split -> fused affine ----------------
__global__ __launch_bounds__(512)
void fstats_part(const u16* __restrict__ gb, float* __restrict__ ps, float* __restrict__ pq){
  int b = blockIdx.x, g = b >> 3, chunk = b & 7, c = threadIdx.x;
  const u16* base = gb + (size_t)g*NNODE*HFF + (size_t)chunk*64*HFF;
  float s = 0.f, q = 0.f;
  for (int i = 0; i < 64; ++i){
    float v = bf2f(base[(size_t)i*HFF + c]);
    s += v; q += v*v;
  }
  ps[b*HFF + c] = s; pq[b*HFF + c] = q;
}
__global__ __launch_bounds__(512)
void fstats_comb(const float* __restrict__ ps, const float* __restrict__ pq,
                 const float* __restrict__ gamma, const float* __restrict__ beta,
                 const float* __restrict__ alpha, float* __restrict__ nA, float* __restrict__ nB){
  int g = blockIdx.x, c = threadIdx.x;
  float s = 0.f, q = 0.f;
  #pragma unroll
  for (int j = 0; j < 8; ++j){ s += ps[(g*8+j)*HFF + c]; q += pq[(g*8+j)*HFF + c]; }
  float mean = s * (1.f/NNODE);
  float msq  = q * (1.f/NNODE);
  float a = alpha[c];
  float invv = rsqrtf(msq - mean*mean*a*(2.f-a) + EPSV);
  float ga = gamma[c]*invv;
  nA[g*HFF + c] = ga;
  nB[g*HFF + c] = beta[c] - ga*a*mean;
}

extern "C" void kernel_launch(void* const* d_in, const int* in_sizes, int n_in,
                              void* d_out, int out_size, void* d_ws, size_t ws_size,
                              hipStream_t stream){
  const float* x_in = (const float*)d_in[0];
  const int*   eidx = (const int*)d_in[1];
  const float* ea   = (const float*)d_in[2];
  const float* Wq   = (const float*)d_in[4];
  const float* bq   = (const float*)d_in[5];
  const float* Wk   = (const float*)d_in[6];
  const float* bk   = (const float*)d_in[7];
  const float* Wv   = (const float*)d_in[8];
  const float* bv   = (const float*)d_in[9];
  const float* We   = (const float*)d_in[10];
  const float* Wsk  = (const float*)d_in[11];
  const float* bsk  = (const float*)d_in[12];
  const float* gn_g = (const float*)d_in[13];
  const float* gn_b = (const float*)d_in[14];
  const float* gn_a = (const float*)d_in[15];
  const float* ffW1 = (const float*)d_in[16];
  const float* ffb1 = (const float*)d_in[17];
  const float* fgn_g= (const float*)d_in[18];
  const float* fgn_b= (const float*)d_in[19];
  const float* fgn_a= (const float*)d_in[20];
  const float* ffW2 = (const float*)d_in[21];
  const float* ffb2 = (const float*)d_in[22];
  const int* srcA = eidx;
  const int* dstA = eidx + NEDGE;

  char* w = (char*)d_ws;
  auto alloc = [&](size_t bytes)->char*{ char* p = w; w += (bytes + 255) & ~(size_t)255; return p; };
  int* counts  = (int*)alloc((size_t)NTOT*4);
  int* row_ptr = (int*)alloc((size_t)(NTOT+1)*4);
  int* ssrc    = (int*)alloc((size_t)NEDGE*4);
  int* inv     = (int*)alloc((size_t)NEDGE*4);        // orig edge -> sorted pos
  u16* e_bf    = (u16*)alloc((size_t)3*NEDGE*DDIM*2); // 384 MiB: e for all 3 layers (sorted order)
  u16* x_bf    = (u16*)alloc((size_t)NTOT*DDIM*2);    // bf16 layer activations (x / gelu'd y / y3)
  u16* qb      = (u16*)alloc((size_t)NTOT*DDIM*2);
  u16* kb      = (u16*)alloc((size_t)NTOT*DDIM*2);
  u16* vb      = (u16*)alloc((size_t)NTOT*DDIM*2);
  u16* skipb   = (u16*)alloc((size_t)NTOT*DDIM*2);    // bf16 skip
  float* nAb   = (float*)alloc((size_t)NB*HFF*4);
  float* nBb   = (float*)alloc((size_t)NB*HFF*4);
  float* psbuf = (float*)alloc((size_t)NB*8*HFF*4);
  float* pqbuf = (float*)alloc((size_t)NB*8*HFF*4);
  u16* g_bf  = e_bf;   // FFN1 output aliases e (attn done by then)
  float* pool = (float*)d_out + (size_t)NTOT*DDIM;

  // prep (counts=0, pool=0, x->bf16) + CSR build
  prep_kernel<<<NTOT*DDIM/1024, 256, 0, stream>>>(x_in, x_bf, counts, pool);
  hist_kernel<<<NEDGE/256, 256, 0, stream>>>(dstA, counts);
  scan_kernel<<<1, 1024, 0, stream>>>(counts, row_ptr, counts);
  scatter_kernel<<<NEDGE/256, 256, 0, stream>>>(srcA, dstA, counts, ssrc, inv);

  // e_l = ea @ We[l] for all 3 layers: streaming reads (orig order), scatter writes (sorted)
  egemm3_kernel<<<256, 512, 0, stream>>>(ea, inv, We, e_bf, NEDGE/256);

  for (int l = 0; l < 3; ++l){
    // q,k,v,skip (all bf16); layers 1,2 read gelu'd bf16 with fused norm affine
    Gemm2Cfg cq = {};
    cq.B[0]=Wq + (size_t)l*DDIM*DDIM; cq.B[1]=Wk + (size_t)l*DDIM*DDIM;
    cq.B[2]=Wv + (size_t)l*DDIM*DDIM; cq.B[3]=Wsk + (size_t)l*DDIM*DDIM;
    cq.bias[0]=bq + l*DDIM; cq.bias[1]=bk + l*DDIM; cq.bias[2]=bv + l*DDIM; cq.bias[3]=bsk + l*DDIM;
    cq.o16[0]=qb; cq.o16[1]=kb; cq.o16[2]=vb; cq.o16[3]=skipb;
    cq.ldb = DDIM; cq.ld_out = DDIM; cq.bcolmul = 0; cq.ocolmul = 0; cq.gelu = 0;
    cq.mtiles = NTOT/128;
    if (l == 0){
      gemm2_kernel<false><<<dim3(NTOT/128, 4), 256, 0, stream>>>(x_bf, cq);
    } else {
      cq.nA = nAb; cq.nBp = nBb;
      gemm2_kernel<true><<<dim3(NTOT/128, 4), 256, 0, stream>>>(x_bf, cq);
    }

    if (l < 2){
      attn_kernel<1><<<NTOT/4, 256, 0, stream>>>(row_ptr, ssrc,
          e_bf + (size_t)l*NEDGE*DDIM, qb, kb, vb, skipb, x_bf);
      gstats_part<<<NB*8, 128, 0, stream>>>(x_bf, psbuf, pqbuf);
      gstats_comb<<<NB, 128, 0, stream>>>(psbuf, pqbuf,
          gn_g + l*DDIM, gn_b + l*DDIM, gn_a + l*DDIM, nAb, nBb);
    } else {
      attn_kernel<0><<<NTOT/4, 256, 0, stream>>>(row_ptr, ssrc,
          e_bf + (size_t)l*NEDGE*DDIM, qb, kb, vb, skipb, x_bf);
    }
  }

  // FFN1: g = gelu(y3 @ ffW1 + ffb1) (bf16, aliases e region); A = y3 bf16
  Gemm2Cfg c1 = {};
  for (int i2 = 0; i2 < 4; ++i2){ c1.B[i2] = ffW1; c1.bias[i2] = ffb1; c1.o16[i2] = g_bf; }
  c1.ldb = HFF; c1.ld_out = HFF; c1.bcolmul = 128; c1.ocolmul = 128; c1.gelu = 1;
  c1.mtiles = NTOT/128;
  gemm2_kernel<false><<<dim3(NTOT/128, 4), 256, 0, stream>>>(x_bf, c1);

  fstats_part<<<NB*8, 512, 0, stream>>>(g_bf, psbuf, pqbuf);
  fstats_comb<<<NB, 512, 0, stream>>>(psbuf, pqbuf, fgn_g, fgn_b, fgn_a, nAb, nBb);

  // FFN2 (K=512): x_out = norm(g) @ ffW2 + ffb2 -> d_out, norm fused into A-staging, fused mean-pool
  GemmCfg c2 = {};
  for (int i2 = 0; i2 < 4; ++i2){ c2.B[i2] = ffW2; c2.bias[i2] = ffb2; c2.o32[i2] = (float*)d_out; }
  c2.ldb = DDIM; c2.ld_out = DDIM; c2.K = HFF; c2.bcolmul = 0; c2.ocolmul = 0; c2.gelu = 0;
  c2.pool = pool;
  c2.nA = nAb; c2.nBp = nBb;
  gemm_old<<<dim3(NTOT/128, 1), 256, 0, stream>>>(g_bf, c2);
}